// Round 17
// baseline (217.294 us; speedup 1.0000x reference)
//
#include <hip/hip_runtime.h>

#define NXc 468
#define NYc 468
#define CANVASc (468 * 468)   // 219024
#define NPTS 400000
#define RUN 16                // boundary granularity (kS, v1c/vmc indexing)
#define WPTS 32               // points per kB wave (R15: two RUNs share weights)
#define NRUNS (NPTS / RUN)    // 25000 boundaries
#define NWAVE (NPTS / WPTS)   // 12500 kB waves
#define GPTS ((NPTS + 255) / 256)      // 1563
#define GVOX ((CANVASc + 255) / 256)   // 856
#define GBND (NRUNS / 4)               // 6250 (kS: wave-per-boundary)

#define PCMIN_X (-74.88f)
#define PCMIN_Y (-74.88f)
#define VOX_X 0.32f
#define VOX_Y 0.32f
#define OFF_X (-74.72f)
#define OFF_Y (-74.72f)
#define OFF_Z (1.0f)

typedef __attribute__((ext_vector_type(8))) short v8s;   // 8 bf16 (4 VGPRs)
typedef __attribute__((ext_vector_type(4))) float v4f;   // MFMA acc

static_assert(sizeof(__bf16) == 2, "bf16 must be 2 bytes");

__device__ __forceinline__ int rli(int x, int p) {
    return __builtin_amdgcn_readlane(x, p);
}
__device__ __forceinline__ float rlf(float x, int p) {
    return __int_as_float(__builtin_amdgcn_readlane(__float_as_int(x), p));
}

// Native bf16 split: hi = RNE(f), lo = RNE(f - hi).
__device__ __forceinline__ void split8(const float* f, v8s& h, v8s& l) {
    #pragma unroll
    for (int i = 0; i < 8; i += 2) {
        __bf16 h0 = (__bf16)f[i];
        __bf16 h1 = (__bf16)f[i + 1];
        h[i]     = __builtin_bit_cast(short, h0);
        h[i + 1] = __builtin_bit_cast(short, h1);
        float l0 = f[i]     - (float)h0;
        float l1 = f[i + 1] - (float)h1;
        l[i]     = __builtin_bit_cast(short, (__bf16)l0);
        l[i + 1] = __builtin_bit_cast(short, (__bf16)l1);
    }
}

// Bins MUST stay bit-identical everywhere (fp32 division, no reciprocal).
__device__ __forceinline__ int voxel_cell(float x, float y, int& cx, int& cy) {
    cx = (int)floorf((x - PCMIN_X) / VOX_X);
    cy = (int)floorf((y - PCMIN_Y) / VOX_Y);
    cx = min(max(cx, 0), NXc - 1);
    cy = min(max(cy, 0), NYc - 1);
    return cy * NXc + cx;
}

// kW body: bf16 hi/lo B-fragments for W2 (4 tiles x 4 K-chunks) and W1.
__device__ __forceinline__ void kw_body(int tid,
                                        const float* __restrict__ W1,
                                        const float* __restrict__ W2,
                                        v8s* __restrict__ w1frag,
                                        v8s* __restrict__ w2frag) {
    if (tid < 1024) {
        int f = tid >> 6, lane = tid & 63;
        int t = f >> 2, c = f & 3;
        int q = lane >> 4, n = lane & 15;
        float v[8];
        #pragma unroll
        for (int i = 0; i < 8; i++) v[i] = W2[(c * 32 + q * 8 + i) * 64 + t * 16 + n];
        v8s h, l;
        split8(v, h, l);
        w2frag[(f * 2 + 0) * 64 + lane] = h;
        w2frag[(f * 2 + 1) * 64 + lane] = l;
    } else if (tid < 1280) {
        int f = (tid - 1024) >> 6, lane = (tid - 1024) & 63;
        int q = lane >> 4, n = lane & 15;
        float v[8];
        #pragma unroll
        for (int i = 0; i < 8; i++) {
            int k = q * 8 + i;
            v[i] = (k < 11) ? W1[k * 64 + f * 16 + n] : 0.f;
        }
        v8s h, l;
        split8(v, h, l);
        w1frag[(f * 2 + 0) * 64 + lane] = h;
        w1frag[(f * 2 + 1) * 64 + lane] = l;
    }
}

// Pass 0: counts + per-point RANK + packed cell; tail builds W-fragments.
__global__ __launch_bounds__(256) void k_stats(const float* __restrict__ pts,
                                               int* __restrict__ cnt,
                                               int* __restrict__ rankb,
                                               int* __restrict__ cellu,
                                               const float* __restrict__ W1,
                                               const float* __restrict__ W2,
                                               v8s* __restrict__ w1frag,
                                               v8s* __restrict__ w2frag) {
    int b = blockIdx.x;
    if (b >= GPTS) {
        kw_body((b - GPTS) * 256 + threadIdx.x, W1, W2, w1frag, w2frag);
        return;
    }
    int i = b * 256 + threadIdx.x;
    if (i >= NPTS) return;
    float x = pts[i * 5 + 0], y = pts[i * 5 + 1];
    int cx, cy;
    int fl = voxel_cell(x, y, cx, cy);
    rankb[i] = atomicAdd(&cnt[fl], 1);
    cellu[i] = cx | (cy << 16);
}

// Pass 1: exclusive-scan alloc -> cursor (= segment start) + empty-row zero.
__global__ __launch_bounds__(256) void k_alloc(const int* __restrict__ cnt,
                                               int* __restrict__ cursor,
                                               int* __restrict__ gcur,
                                               float4* __restrict__ out4) {
    int v = blockIdx.x * 256 + threadIdx.x;
    int lane = threadIdx.x & 63;
    int c = (v < CANVASc) ? cnt[v] : 0;
    int scan = c;
    #pragma unroll
    for (int off = 1; off < 64; off <<= 1) {
        int t = __shfl_up(scan, off, 64);
        if (lane >= off) scan += t;
    }
    int total = __shfl(scan, 63, 64);
    int base = 0;
    if (lane == 0 && total > 0) base = atomicAdd(gcur, total);
    base = __shfl(base, 0, 64);
    if (v < CANVASc) {
        cursor[v] = base + scan - c;
        if (c == 0) {
            float4 z = make_float4(0.f, 0.f, 0.f, 0.f);
            float4* o = out4 + (size_t)v * 16;
            #pragma unroll
            for (int i = 0; i < 16; i++) o[i] = z;
        }
    }
}

__device__ __forceinline__ void gather_pt(const float* __restrict__ pts, int pi,
                                          float4& A, float& e1) {
    const float* pp = pts + (size_t)pi * 5;
    __builtin_memcpy(&A, pp, 16);   // 4B-aligned dwordx4
    e1 = pp[4];
}

// Pass 2: ATOMIC-FREE record scatter. pos = cursor[fl] + rank[i].
__global__ __launch_bounds__(256) void k_scatter(const float* __restrict__ pts,
                                                 const int* __restrict__ cursor,
                                                 const int* __restrict__ rankb,
                                                 const int* __restrict__ cellu,
                                                 float4* __restrict__ pos4,
                                                 float* __restrict__ e1b,
                                                 int* __restrict__ cellb) {
    int i = blockIdx.x * 256 + threadIdx.x;
    if (i >= NPTS) return;
    float4 A; float e1;
    gather_pt(pts, i, A, e1);
    int cell = cellu[i];
    int cx = cell & 0xFFFF, cy = cell >> 16;
    int fl = cy * NXc + cx;
    int pos = cursor[fl] + rankb[i];
    pos4[pos] = A;
    e1b[pos] = e1;
    cellb[pos] = cell;
}

// kS: one wave per 16-point boundary. Seam voxel: zero out row, store the
// full-voxel mean -> vmc[w], seam v1 row -> v1c[w].
__global__ __launch_bounds__(256) void kS(const int* __restrict__ cnt,
                                          const int* __restrict__ cursor,
                                          const float4* __restrict__ pos4,
                                          const float* __restrict__ e1b,
                                          const int* __restrict__ cellb,
                                          const float* __restrict__ W1,
                                          float4* __restrict__ vmc,
                                          float* __restrict__ v1c,
                                          float* __restrict__ out) {
    int j = threadIdx.x & 63;
    int wslot = threadIdx.x >> 6;
    int w = blockIdx.x * 4 + wslot;           // boundary id
    if (w == 0 || w >= NRUNS) return;
    int bb = w * RUN;
    int ca = cellb[bb - 1], cb0 = cellb[bb];
    if (ca != cb0) return;                    // no voxel spans this boundary
    int cx = ca & 0xFFFF, cy = ca >> 16;
    int v = cy * NXc + cx;
    int c = cnt[v];
    int start = cursor[v];
    out[(size_t)v * 64 + j] = 0.f;            // row only ever sees atomicMax

    float sx = 0.f, sy = 0.f, sz = 0.f;
    for (int pb = 0; pb < c; pb += 64) {
        int pc = min(c - pb, 64);
        if (j < pc) {
            float4 A = pos4[start + pb + j];
            sx += A.x; sy += A.y; sz += A.z;
        }
    }
    #pragma unroll
    for (int off = 1; off < 64; off <<= 1) {
        sx += __shfl_xor(sx, off, 64);
        sy += __shfl_xor(sy, off, 64);
        sz += __shfl_xor(sz, off, 64);
    }
    float inv = 1.0f / (float)c;
    float mx = sx * inv, my = sy * inv, mz = sz * inv;
    if (j == 0) vmc[w] = make_float4(mx, my, mz, 0.f);

    float wgt[11];
    #pragma unroll
    for (int k = 0; k < 11; k++) wgt[k] = W1[k * 64 + j];
    float vmax = 0.f;
    for (int pb = 0; pb < c; pb += 64) {
        int pc = min(c - pb, 64);
        float f[11];
        #pragma unroll
        for (int k = 0; k < 11; k++) f[k] = 0.f;
        if (j < pc) {
            int idx = start + pb + j;
            float4 A = pos4[idx];
            float e1 = e1b[idx];
            int cell = cellb[idx];
            int ccx = cell & 0xFFFF, ccy = cell >> 16;
            f[0] = A.x; f[1] = A.y; f[2] = A.z; f[3] = A.w; f[4] = e1;
            f[5] = A.x - mx; f[6] = A.y - my; f[7] = A.z - mz;
            f[8] = A.x - (ccx * VOX_X + OFF_X);
            f[9] = A.y - (ccy * VOX_Y + OFF_Y);
            f[10] = A.z - OFF_Z;
        }
        for (int p = 0; p < pc; p++) {
            float acc = 0.f;
            #pragma unroll
            for (int k = 0; k < 11; k++)
                acc = fmaf(rlf(f[k], p), wgt[k], acc);
            vmax = fmaxf(vmax, acc);
        }
    }
    v1c[(size_t)w * 64 + j] = vmax;
}

#define PSTR 68   // LDS row stride (floats); 68 -> 2-way bank alias (free)

// kB (R17): WPTS=32 weight-sharing kept; 64-thread blocks (1 wave) so block
// LDS drops 17.4 -> 8.7 KB — up to 16-18 blocks/CU, each independently
// schedulable (R16 A/B proved kB is latency-bound: occupancy up => time down).
__global__ __launch_bounds__(64, 8) void kB(const float4* __restrict__ pos4,
                                          const float* __restrict__ e1b,
                                          const int* __restrict__ cellb,
                                          const float4* __restrict__ vmc,
                                          const v8s* __restrict__ w1frag,
                                          const v8s* __restrict__ w2frag,
                                          const float* __restrict__ v1c,
                                          float* __restrict__ out) {
    __shared__ float spf[WPTS][PSTR];
    int wave = blockIdx.x;                   // 0..NWAVE-1
    int j = threadIdx.x & 63;
    int base = wave * WPTS;

    const int m = j & 15, q = j >> 4;

    // lanes 0..31: points; lane 32: peek base+32; lane 33: peek base-1
    int idx = -1;
    if (j < WPTS) idx = base + j;
    else if (j == 32) idx = (base + WPTS < NPTS) ? base + WPTS : -1;
    else if (j == 33) idx = base - 1;

    int cell = 0, vx = -1;
    if (idx >= 0) {
        cell = cellb[idx];
        vx = (cell >> 16) * NXc + (cell & 0xFFFF);
    }
    float4 A = make_float4(0.f, 0.f, 0.f, 0.f);
    float e1 = 0.f;
    if (j < WPTS) { A = pos4[idx]; e1 = e1b[idx]; }

    const int first0 = rli(vx, 0),  last0 = rli(vx, 15);
    const int first1 = rli(vx, 16), last1 = rli(vx, 31);
    const bool firstExt0 = (rli(vx, 33) == first0);
    const bool midExt    = (first1 == last0);        // voxel spans run0|run1
    const bool lastExt0  = midExt;
    const bool firstExt1 = midExt;
    const bool lastExt1  = (rli(vx, 32) == last1);

    // One ballot; run boundaries forced at bits 0 and 16 (interior segments
    // never cross 16 — crossing voxels are ext and use the kS row).
    int vx_prev = __shfl_up(vx, 1, 64);
    unsigned long long B =
        __ballot((j < WPTS) && ((j == 0) || (j == 16) || (vx != vx_prev)));

    // tile0 point P0=m, tile1 point P1=16+m (per-lane)
    const int P1 = 16 + m;
    int s0_ = 63 - __builtin_clzll(B & ((2ULL << m) - 1ULL));
    int e0_ = m + 1 + (int)__builtin_ctzll((B | (1ULL << WPTS)) >> (m + 1));
    int s1_ = 63 - __builtin_clzll(B & ((2ULL << P1) - 1ULL));
    int e1_ = P1 + 1 + (int)__builtin_ctzll((B | (1ULL << WPTS)) >> (P1 + 1));

    int vxm0 = __builtin_amdgcn_ds_bpermute(m << 2, vx);
    int vxm1 = __builtin_amdgcn_ds_bpermute(P1 << 2, vx);
    const bool fext0 = (vxm0 == first0 && firstExt0);
    const bool ext0  = fext0 || (vxm0 == last0 && lastExt0);
    const int  bidx0 = fext0 ? (2 * wave) : (2 * wave + 1);
    const bool fext1 = (vxm1 == first1 && firstExt1);
    const bool ext1  = fext1 || (vxm1 == last1 && lastExt1);
    const int  bidx1 = fext1 ? (2 * wave + 1) : (2 * wave + 2);

    // own-point mean (for feature rows; j<32). For j<16 own==tile0 lane data;
    // for j in 16..31 own==tile1 lane data (m==j&15 matches).
    float mx = 0.f, my = 0.f, mz = 0.f, fcx = 0.f, fcy = 0.f, fcz = 0.f;
    if (j < WPTS) {
        bool own_ext  = (j < 16) ? ext0 : ext1;
        int  own_bidx = (j < 16) ? bidx0 : bidx1;
        int  own_s    = (j < 16) ? s0_ : s1_;
        int  own_e    = (j < 16) ? e0_ : e1_;
        if (own_ext) {
            float4 mv = vmc[own_bidx];
            mx = mv.x; my = mv.y; mz = mv.z;
        } else {
            float sx = 0.f, sy = 0.f, sz = 0.f;
            for (int p = own_s; p < own_e; p++) {
                sx += __shfl(A.x, p, 64);
                sy += __shfl(A.y, p, 64);
                sz += __shfl(A.z, p, 64);
            }
            float inv = 1.0f / (float)(own_e - own_s);
            mx = sx * inv; my = sy * inv; mz = sz * inv;
        }
        int cx = cell & 0xFFFF, cy = cell >> 16;
        fcx = A.x - (cx * VOX_X + OFF_X);
        fcy = A.y - (cy * VOX_Y + OFF_Y);
        fcz = A.z - OFF_Z;
    }

    // ---- phase 1: features -> LDS (32 rows), 2-tile MFMA sharing w1 frags
    if (j < WPTS) {
        float* row = spf[j];
        row[0] = A.x; row[1] = A.y; row[2] = A.z; row[3] = A.w; row[4] = e1;
        row[5] = A.x - mx; row[6] = A.y - my; row[7] = A.z - mz;
        row[8] = fcx; row[9] = fcy; row[10] = fcz;
        #pragma unroll
        for (int t = 11; t < 16; t++) row[t] = 0.f;
    }
    __builtin_amdgcn_wave_barrier();

    v8s fh0 = {0,0,0,0,0,0,0,0}, fl0 = {0,0,0,0,0,0,0,0};
    v8s fh1 = {0,0,0,0,0,0,0,0}, fl1 = {0,0,0,0,0,0,0,0};
    if (q < 2) {
        float f8[8];
        #pragma unroll
        for (int i = 0; i < 8; i++) f8[i] = spf[m][q * 8 + i];
        split8(f8, fh0, fl0);
        #pragma unroll
        for (int i = 0; i < 8; i++) f8[i] = spf[16 + m][q * 8 + i];
        split8(f8, fh1, fl1);
    }
    v4f d0[4], d1[4];
    #pragma unroll
    for (int t = 0; t < 4; t++) {
        v8s bh = w1frag[(t * 2 + 0) * 64 + j];
        v8s bl = w1frag[(t * 2 + 1) * 64 + j];
        v4f a0 = {0.f, 0.f, 0.f, 0.f}, a1 = {0.f, 0.f, 0.f, 0.f};
        a0 = __builtin_amdgcn_mfma_f32_16x16x32_bf16(fh0, bh, a0, 0, 0, 0);
        a0 = __builtin_amdgcn_mfma_f32_16x16x32_bf16(fl0, bh, a0, 0, 0, 0);
        a0 = __builtin_amdgcn_mfma_f32_16x16x32_bf16(fh0, bl, a0, 0, 0, 0);
        a1 = __builtin_amdgcn_mfma_f32_16x16x32_bf16(fh1, bh, a1, 0, 0, 0);
        a1 = __builtin_amdgcn_mfma_f32_16x16x32_bf16(fl1, bh, a1, 0, 0, 0);
        a1 = __builtin_amdgcn_mfma_f32_16x16x32_bf16(fh1, bl, a1, 0, 0, 0);
        d0[t] = a0; d1[t] = a1;
    }
    __builtin_amdgcn_wave_barrier();   // feature reads done before overwrite
    #pragma unroll
    for (int t = 0; t < 4; t++)
        #pragma unroll
        for (int r = 0; r < 4; r++) {
            spf[q * 4 + r][t * 16 + m]      = fmaxf(d0[t][r], 0.f);
            spf[16 + q * 4 + r][t * 16 + m] = fmaxf(d1[t][r], 0.f);
        }
    __builtin_amdgcn_wave_barrier();

    // ---- phase 2: A-frags for both tiles; shared w2 frags in the t-loop
    float vf0[16], vf1[16];
    if (ext0) {
        const float* vr = v1c + (size_t)bidx0 * 64 + q * 8;
        #pragma unroll
        for (int c = 0; c < 2; c++)
            #pragma unroll
            for (int i = 0; i < 8; i++) vf0[c * 8 + i] = vr[c * 32 + i];
    }
    if (ext1) {
        const float* vr = v1c + (size_t)bidx1 * 64 + q * 8;
        #pragma unroll
        for (int c = 0; c < 2; c++)
            #pragma unroll
            for (int i = 0; i < 8; i++) vf1[c * 8 + i] = vr[c * 32 + i];
    }

    v8s ah0[4], al0[4], ah1[4], al1[4];
    #pragma unroll
    for (int c = 0; c < 2; c++) {
        float f[8];
        #pragma unroll
        for (int i = 0; i < 8; i++) f[i] = spf[m][c * 32 + q * 8 + i];
        split8(f, ah0[c], al0[c]);
        #pragma unroll
        for (int i = 0; i < 8; i++) f[i] = spf[16 + m][c * 32 + q * 8 + i];
        split8(f, ah1[c], al1[c]);
    }
    if (!ext0) {
        #pragma unroll
        for (int i = 0; i < 16; i++) vf0[i] = 0.f;
        for (int p = s0_; p < e0_; p++) {
            const float* row = spf[p];
            #pragma unroll
            for (int i = 0; i < 8; i++) {
                vf0[i]     = fmaxf(vf0[i],     row[q * 8 + i]);
                vf0[8 + i] = fmaxf(vf0[8 + i], row[32 + q * 8 + i]);
            }
        }
    }
    if (!ext1) {
        #pragma unroll
        for (int i = 0; i < 16; i++) vf1[i] = 0.f;
        for (int p = s1_; p < e1_; p++) {
            const float* row = spf[p];
            #pragma unroll
            for (int i = 0; i < 8; i++) {
                vf1[i]     = fmaxf(vf1[i],     row[q * 8 + i]);
                vf1[8 + i] = fmaxf(vf1[8 + i], row[32 + q * 8 + i]);
            }
        }
    }
    split8(vf0 + 0, ah0[2], al0[2]);
    split8(vf0 + 8, ah0[3], al0[3]);
    split8(vf1 + 0, ah1[2], al1[2]);
    split8(vf1 + 8, ah1[3], al1[3]);
    __builtin_amdgcn_wave_barrier();   // A reads done before D overwrites

    #pragma unroll
    for (int t = 0; t < 4; t++) {
        v8s bh[4], bl[4];
        #pragma unroll
        for (int c = 0; c < 4; c++) {
            bh[c] = w2frag[((t * 4 + c) * 2 + 0) * 64 + j];
            bl[c] = w2frag[((t * 4 + c) * 2 + 1) * 64 + j];
        }
        v4f a0 = {0.f, 0.f, 0.f, 0.f}, a1 = {0.f, 0.f, 0.f, 0.f};
        #pragma unroll
        for (int c = 0; c < 4; c++) {
            a0 = __builtin_amdgcn_mfma_f32_16x16x32_bf16(ah0[c], bh[c], a0, 0, 0, 0);
            a0 = __builtin_amdgcn_mfma_f32_16x16x32_bf16(al0[c], bh[c], a0, 0, 0, 0);
            a0 = __builtin_amdgcn_mfma_f32_16x16x32_bf16(ah0[c], bl[c], a0, 0, 0, 0);
            a1 = __builtin_amdgcn_mfma_f32_16x16x32_bf16(ah1[c], bh[c], a1, 0, 0, 0);
            a1 = __builtin_amdgcn_mfma_f32_16x16x32_bf16(al1[c], bh[c], a1, 0, 0, 0);
            a1 = __builtin_amdgcn_mfma_f32_16x16x32_bf16(ah1[c], bl[c], a1, 0, 0, 0);
        }
        #pragma unroll
        for (int r = 0; r < 4; r++) {
            spf[q * 4 + r][t * 16 + m]      = a0[r];
            spf[16 + q * 4 + r][t * 16 + m] = a1[r];
        }
    }
    __builtin_amdgcn_wave_barrier();

    // ---- epilogue: per-run serial segment-max store (run0 then run1)
    {
        int vprev = first0;
        float smax = -3.4e38f;
        for (int p = 0; p < 16; p++) {
            int vp = rli(vx, p);
            if (vp != vprev) {
                float r = fmaxf(smax, 0.f);
                size_t o = (size_t)vprev * 64 + j;
                bool ua = (vprev == first0 && firstExt0) ||
                          (vprev == last0 && lastExt0);
                if (ua) atomicMax((int*)out + o, __float_as_int(r));
                else out[o] = r;
                vprev = vp; smax = -3.4e38f;
            }
            smax = fmaxf(smax, spf[p][j]);
        }
        float r = fmaxf(smax, 0.f);
        size_t o = (size_t)vprev * 64 + j;
        bool ua = (vprev == first0 && firstExt0) ||
                  (vprev == last0 && lastExt0);
        if (ua) atomicMax((int*)out + o, __float_as_int(r));
        else out[o] = r;
    }
    {
        int vprev = first1;
        float smax = -3.4e38f;
        for (int p = 16; p < 32; p++) {
            int vp = rli(vx, p);
            if (vp != vprev) {
                float r = fmaxf(smax, 0.f);
                size_t o = (size_t)vprev * 64 + j;
                bool ua = (vprev == first1 && firstExt1) ||
                          (vprev == last1 && lastExt1);
                if (ua) atomicMax((int*)out + o, __float_as_int(r));
                else out[o] = r;
                vprev = vp; smax = -3.4e38f;
            }
            smax = fmaxf(smax, spf[p][j]);
        }
        float r = fmaxf(smax, 0.f);
        size_t o = (size_t)vprev * 64 + j;
        bool ua = (vprev == first1 && firstExt1) ||
                  (vprev == last1 && lastExt1);
        if (ua) atomicMax((int*)out + o, __float_as_int(r));
        else out[o] = r;
    }
}

extern "C" void kernel_launch(void* const* d_in, const int* in_sizes, int n_in,
                              void* d_out, int out_size, void* d_ws, size_t ws_size,
                              hipStream_t stream) {
    const float* pts = (const float*)d_in[0];
    const float* W1  = (const float*)d_in[1];
    const float* W2  = (const float*)d_in[2];
    float* out = (float*)d_out;

    float4* vmc    = (float4*)d_ws;                         // NRUNS float4 (400 KB)
    float*  v1c    = (float*)(vmc + NRUNS);                 // NRUNS*64 (6.4 MB)
    float4* pos4   = (float4*)(v1c + (size_t)NRUNS * 64);   // NPTS float4
    float*  e1b    = (float*)(pos4 + NPTS);                 // NPTS
    int*    cellb  = (int*)(e1b + NPTS);                    // NPTS
    int*    rankb  = cellb + NPTS;                          // NPTS
    int*    cellu  = rankb + NPTS;                          // NPTS
    v8s*    w2frag = (v8s*)(cellu + NPTS);                  // 2048 v8s
    v8s*    w1frag = w2frag + 2048;                         // 512 v8s
    int*    cnt    = (int*)(w1frag + 512);                  // CANVAS
    int*    gcur   = cnt + CANVASc;                         // 1
    int*    cursor = gcur + 1;                              // CANVAS

    hipMemsetAsync(cnt, 0, (size_t)(CANVASc + 1) * 4, stream);   // cnt + gcur

    k_stats  <<<GPTS + 5, 256, 0, stream>>>(pts, cnt, rankb, cellu,
                                            W1, W2, w1frag, w2frag);
    k_alloc  <<<GVOX, 256, 0, stream>>>(cnt, cursor, gcur, (float4*)out);
    k_scatter<<<GPTS, 256, 0, stream>>>(pts, cursor, rankb, cellu,
                                        pos4, e1b, cellb);
    kS       <<<GBND, 256, 0, stream>>>(cnt, cursor, pos4, e1b, cellb,
                                        W1, vmc, v1c, out);
    kB       <<<NWAVE, 64, 0, stream>>>(pos4, e1b, cellb, vmc, w1frag,
                                        w2frag, v1c, out);
}

// Round 18
// 212.364 us; speedup vs baseline: 1.0232x; 1.0232x over previous
//
#include <hip/hip_runtime.h>

#define NXc 468
#define NYc 468
#define CANVASc (468 * 468)   // 219024
#define NPTS 400000
#define RUN 16                // boundary granularity (kS, v1c/vmc indexing)
#define WPTS 32               // points per kB wave (R15: two RUNs share weights)
#define NRUNS (NPTS / RUN)    // 25000 boundaries
#define NWAVE (NPTS / WPTS)   // 12500 kB waves
#define GPTS ((NPTS + 255) / 256)      // 1563
#define GVOX ((CANVASc + 255) / 256)   // 856
#define GBND (NRUNS / 4)               // 6250 (kS: wave-per-boundary)
#define GKB  (NWAVE / 2)               // 6250 (kB blocks: 2 waves/block — R16 optimum)

#define PCMIN_X (-74.88f)
#define PCMIN_Y (-74.88f)
#define VOX_X 0.32f
#define VOX_Y 0.32f
#define OFF_X (-74.72f)
#define OFF_Y (-74.72f)
#define OFF_Z (1.0f)

typedef __attribute__((ext_vector_type(8))) short v8s;   // 8 bf16 (4 VGPRs)
typedef __attribute__((ext_vector_type(4))) float v4f;   // MFMA acc

static_assert(sizeof(__bf16) == 2, "bf16 must be 2 bytes");

__device__ __forceinline__ int rli(int x, int p) {
    return __builtin_amdgcn_readlane(x, p);
}
__device__ __forceinline__ float rlf(float x, int p) {
    return __int_as_float(__builtin_amdgcn_readlane(__float_as_int(x), p));
}

// Native bf16 split: hi = RNE(f), lo = RNE(f - hi).
__device__ __forceinline__ void split8(const float* f, v8s& h, v8s& l) {
    #pragma unroll
    for (int i = 0; i < 8; i += 2) {
        __bf16 h0 = (__bf16)f[i];
        __bf16 h1 = (__bf16)f[i + 1];
        h[i]     = __builtin_bit_cast(short, h0);
        h[i + 1] = __builtin_bit_cast(short, h1);
        float l0 = f[i]     - (float)h0;
        float l1 = f[i + 1] - (float)h1;
        l[i]     = __builtin_bit_cast(short, (__bf16)l0);
        l[i + 1] = __builtin_bit_cast(short, (__bf16)l1);
    }
}

// Bins MUST stay bit-identical everywhere (fp32 division, no reciprocal).
__device__ __forceinline__ int voxel_cell(float x, float y, int& cx, int& cy) {
    cx = (int)floorf((x - PCMIN_X) / VOX_X);
    cy = (int)floorf((y - PCMIN_Y) / VOX_Y);
    cx = min(max(cx, 0), NXc - 1);
    cy = min(max(cy, 0), NYc - 1);
    return cy * NXc + cx;
}

// kW body: bf16 hi/lo B-fragments for W2 (4 tiles x 4 K-chunks) and W1.
__device__ __forceinline__ void kw_body(int tid,
                                        const float* __restrict__ W1,
                                        const float* __restrict__ W2,
                                        v8s* __restrict__ w1frag,
                                        v8s* __restrict__ w2frag) {
    if (tid < 1024) {
        int f = tid >> 6, lane = tid & 63;
        int t = f >> 2, c = f & 3;
        int q = lane >> 4, n = lane & 15;
        float v[8];
        #pragma unroll
        for (int i = 0; i < 8; i++) v[i] = W2[(c * 32 + q * 8 + i) * 64 + t * 16 + n];
        v8s h, l;
        split8(v, h, l);
        w2frag[(f * 2 + 0) * 64 + lane] = h;
        w2frag[(f * 2 + 1) * 64 + lane] = l;
    } else if (tid < 1280) {
        int f = (tid - 1024) >> 6, lane = (tid - 1024) & 63;
        int q = lane >> 4, n = lane & 15;
        float v[8];
        #pragma unroll
        for (int i = 0; i < 8; i++) {
            int k = q * 8 + i;
            v[i] = (k < 11) ? W1[k * 64 + f * 16 + n] : 0.f;
        }
        v8s h, l;
        split8(v, h, l);
        w1frag[(f * 2 + 0) * 64 + lane] = h;
        w1frag[(f * 2 + 1) * 64 + lane] = l;
    }
}

// Pass 0: counts + per-point RANK + packed cell; tail builds W-fragments.
__global__ __launch_bounds__(256) void k_stats(const float* __restrict__ pts,
                                               int* __restrict__ cnt,
                                               int* __restrict__ rankb,
                                               int* __restrict__ cellu,
                                               const float* __restrict__ W1,
                                               const float* __restrict__ W2,
                                               v8s* __restrict__ w1frag,
                                               v8s* __restrict__ w2frag) {
    int b = blockIdx.x;
    if (b >= GPTS) {
        kw_body((b - GPTS) * 256 + threadIdx.x, W1, W2, w1frag, w2frag);
        return;
    }
    int i = b * 256 + threadIdx.x;
    if (i >= NPTS) return;
    float x = pts[i * 5 + 0], y = pts[i * 5 + 1];
    int cx, cy;
    int fl = voxel_cell(x, y, cx, cy);
    rankb[i] = atomicAdd(&cnt[fl], 1);
    cellu[i] = cx | (cy << 16);
}

// Pass 1: exclusive-scan alloc -> cursor (= segment start) + empty-row zero.
__global__ __launch_bounds__(256) void k_alloc(const int* __restrict__ cnt,
                                               int* __restrict__ cursor,
                                               int* __restrict__ gcur,
                                               float4* __restrict__ out4) {
    int v = blockIdx.x * 256 + threadIdx.x;
    int lane = threadIdx.x & 63;
    int c = (v < CANVASc) ? cnt[v] : 0;
    int scan = c;
    #pragma unroll
    for (int off = 1; off < 64; off <<= 1) {
        int t = __shfl_up(scan, off, 64);
        if (lane >= off) scan += t;
    }
    int total = __shfl(scan, 63, 64);
    int base = 0;
    if (lane == 0 && total > 0) base = atomicAdd(gcur, total);
    base = __shfl(base, 0, 64);
    if (v < CANVASc) {
        cursor[v] = base + scan - c;
        if (c == 0) {
            float4 z = make_float4(0.f, 0.f, 0.f, 0.f);
            float4* o = out4 + (size_t)v * 16;
            #pragma unroll
            for (int i = 0; i < 16; i++) o[i] = z;
        }
    }
}

__device__ __forceinline__ void gather_pt(const float* __restrict__ pts, int pi,
                                          float4& A, float& e1) {
    const float* pp = pts + (size_t)pi * 5;
    __builtin_memcpy(&A, pp, 16);   // 4B-aligned dwordx4
    e1 = pp[4];
}

// Pass 2: ATOMIC-FREE record scatter. pos = cursor[fl] + rank[i].
__global__ __launch_bounds__(256) void k_scatter(const float* __restrict__ pts,
                                                 const int* __restrict__ cursor,
                                                 const int* __restrict__ rankb,
                                                 const int* __restrict__ cellu,
                                                 float4* __restrict__ pos4,
                                                 float* __restrict__ e1b,
                                                 int* __restrict__ cellb) {
    int i = blockIdx.x * 256 + threadIdx.x;
    if (i >= NPTS) return;
    float4 A; float e1;
    gather_pt(pts, i, A, e1);
    int cell = cellu[i];
    int cx = cell & 0xFFFF, cy = cell >> 16;
    int fl = cy * NXc + cx;
    int pos = cursor[fl] + rankb[i];
    pos4[pos] = A;
    e1b[pos] = e1;
    cellb[pos] = cell;
}

// kS: one wave per 16-point boundary. Seam voxel: zero out row, store the
// full-voxel mean -> vmc[w], seam v1 row -> v1c[w].
__global__ __launch_bounds__(256) void kS(const int* __restrict__ cnt,
                                          const int* __restrict__ cursor,
                                          const float4* __restrict__ pos4,
                                          const float* __restrict__ e1b,
                                          const int* __restrict__ cellb,
                                          const float* __restrict__ W1,
                                          float4* __restrict__ vmc,
                                          float* __restrict__ v1c,
                                          float* __restrict__ out) {
    int j = threadIdx.x & 63;
    int wslot = threadIdx.x >> 6;
    int w = blockIdx.x * 4 + wslot;           // boundary id
    if (w == 0 || w >= NRUNS) return;
    int bb = w * RUN;
    int ca = cellb[bb - 1], cb0 = cellb[bb];
    if (ca != cb0) return;                    // no voxel spans this boundary
    int cx = ca & 0xFFFF, cy = ca >> 16;
    int v = cy * NXc + cx;
    int c = cnt[v];
    int start = cursor[v];
    out[(size_t)v * 64 + j] = 0.f;            // row only ever sees atomicMax

    float sx = 0.f, sy = 0.f, sz = 0.f;
    for (int pb = 0; pb < c; pb += 64) {
        int pc = min(c - pb, 64);
        if (j < pc) {
            float4 A = pos4[start + pb + j];
            sx += A.x; sy += A.y; sz += A.z;
        }
    }
    #pragma unroll
    for (int off = 1; off < 64; off <<= 1) {
        sx += __shfl_xor(sx, off, 64);
        sy += __shfl_xor(sy, off, 64);
        sz += __shfl_xor(sz, off, 64);
    }
    float inv = 1.0f / (float)c;
    float mx = sx * inv, my = sy * inv, mz = sz * inv;
    if (j == 0) vmc[w] = make_float4(mx, my, mz, 0.f);

    float wgt[11];
    #pragma unroll
    for (int k = 0; k < 11; k++) wgt[k] = W1[k * 64 + j];
    float vmax = 0.f;
    for (int pb = 0; pb < c; pb += 64) {
        int pc = min(c - pb, 64);
        float f[11];
        #pragma unroll
        for (int k = 0; k < 11; k++) f[k] = 0.f;
        if (j < pc) {
            int idx = start + pb + j;
            float4 A = pos4[idx];
            float e1 = e1b[idx];
            int cell = cellb[idx];
            int ccx = cell & 0xFFFF, ccy = cell >> 16;
            f[0] = A.x; f[1] = A.y; f[2] = A.z; f[3] = A.w; f[4] = e1;
            f[5] = A.x - mx; f[6] = A.y - my; f[7] = A.z - mz;
            f[8] = A.x - (ccx * VOX_X + OFF_X);
            f[9] = A.y - (ccy * VOX_Y + OFF_Y);
            f[10] = A.z - OFF_Z;
        }
        for (int p = 0; p < pc; p++) {
            float acc = 0.f;
            #pragma unroll
            for (int k = 0; k < 11; k++)
                acc = fmaf(rlf(f[k], p), wgt[k], acc);
            vmax = fmaxf(vmax, acc);
        }
    }
    v1c[(size_t)w * 64 + j] = vmax;
}

#define PSTR 68   // LDS row stride (floats); 68 -> 2-way bank alias (free)

// kB (R18 = R16 config, the measured optimum): WPTS=32 weight-sharing;
// 128-thread blocks (2 waves, 17.4 KB LDS). R16 A/B: 256thr/35KB = 25% occ
// (58.7 µs); 128thr/17.4KB = 32% occ (52.0 µs); R17 64thr/8.7KB = 25% occ
// (54.6 µs, workgroup-slot limited). 128 is the sweet spot.
__global__ __launch_bounds__(128, 4) void kB(const float4* __restrict__ pos4,
                                          const float* __restrict__ e1b,
                                          const int* __restrict__ cellb,
                                          const float4* __restrict__ vmc,
                                          const v8s* __restrict__ w1frag,
                                          const v8s* __restrict__ w2frag,
                                          const float* __restrict__ v1c,
                                          float* __restrict__ out) {
    __shared__ float s_pf[2][WPTS][PSTR];
    int wslot = threadIdx.x >> 6;
    int wave = blockIdx.x * 2 + wslot;       // 0..NWAVE-1
    int j = threadIdx.x & 63;
    int base = wave * WPTS;

    const int m = j & 15, q = j >> 4;
    float (*spf)[PSTR] = s_pf[wslot];

    // lanes 0..31: points; lane 32: peek base+32; lane 33: peek base-1
    int idx = -1;
    if (j < WPTS) idx = base + j;
    else if (j == 32) idx = (base + WPTS < NPTS) ? base + WPTS : -1;
    else if (j == 33) idx = base - 1;

    int cell = 0, vx = -1;
    if (idx >= 0) {
        cell = cellb[idx];
        vx = (cell >> 16) * NXc + (cell & 0xFFFF);
    }
    float4 A = make_float4(0.f, 0.f, 0.f, 0.f);
    float e1 = 0.f;
    if (j < WPTS) { A = pos4[idx]; e1 = e1b[idx]; }

    const int first0 = rli(vx, 0),  last0 = rli(vx, 15);
    const int first1 = rli(vx, 16), last1 = rli(vx, 31);
    const bool firstExt0 = (rli(vx, 33) == first0);
    const bool midExt    = (first1 == last0);        // voxel spans run0|run1
    const bool lastExt0  = midExt;
    const bool firstExt1 = midExt;
    const bool lastExt1  = (rli(vx, 32) == last1);

    // One ballot; run boundaries forced at bits 0 and 16 (interior segments
    // never cross 16 — crossing voxels are ext and use the kS row).
    int vx_prev = __shfl_up(vx, 1, 64);
    unsigned long long B =
        __ballot((j < WPTS) && ((j == 0) || (j == 16) || (vx != vx_prev)));

    // tile0 point P0=m, tile1 point P1=16+m (per-lane)
    const int P1 = 16 + m;
    int s0_ = 63 - __builtin_clzll(B & ((2ULL << m) - 1ULL));
    int e0_ = m + 1 + (int)__builtin_ctzll((B | (1ULL << WPTS)) >> (m + 1));
    int s1_ = 63 - __builtin_clzll(B & ((2ULL << P1) - 1ULL));
    int e1_ = P1 + 1 + (int)__builtin_ctzll((B | (1ULL << WPTS)) >> (P1 + 1));

    int vxm0 = __builtin_amdgcn_ds_bpermute(m << 2, vx);
    int vxm1 = __builtin_amdgcn_ds_bpermute(P1 << 2, vx);
    const bool fext0 = (vxm0 == first0 && firstExt0);
    const bool ext0  = fext0 || (vxm0 == last0 && lastExt0);
    const int  bidx0 = fext0 ? (2 * wave) : (2 * wave + 1);
    const bool fext1 = (vxm1 == first1 && firstExt1);
    const bool ext1  = fext1 || (vxm1 == last1 && lastExt1);
    const int  bidx1 = fext1 ? (2 * wave + 1) : (2 * wave + 2);

    // own-point mean (for feature rows; j<32). For j<16 own==tile0 lane data;
    // for j in 16..31 own==tile1 lane data (m==j&15 matches).
    float mx = 0.f, my = 0.f, mz = 0.f, fcx = 0.f, fcy = 0.f, fcz = 0.f;
    if (j < WPTS) {
        bool own_ext  = (j < 16) ? ext0 : ext1;
        int  own_bidx = (j < 16) ? bidx0 : bidx1;
        int  own_s    = (j < 16) ? s0_ : s1_;
        int  own_e    = (j < 16) ? e0_ : e1_;
        if (own_ext) {
            float4 mv = vmc[own_bidx];
            mx = mv.x; my = mv.y; mz = mv.z;
        } else {
            float sx = 0.f, sy = 0.f, sz = 0.f;
            for (int p = own_s; p < own_e; p++) {
                sx += __shfl(A.x, p, 64);
                sy += __shfl(A.y, p, 64);
                sz += __shfl(A.z, p, 64);
            }
            float inv = 1.0f / (float)(own_e - own_s);
            mx = sx * inv; my = sy * inv; mz = sz * inv;
        }
        int cx = cell & 0xFFFF, cy = cell >> 16;
        fcx = A.x - (cx * VOX_X + OFF_X);
        fcy = A.y - (cy * VOX_Y + OFF_Y);
        fcz = A.z - OFF_Z;
    }

    // ---- phase 1: features -> LDS (32 rows), 2-tile MFMA sharing w1 frags
    if (j < WPTS) {
        float* row = spf[j];
        row[0] = A.x; row[1] = A.y; row[2] = A.z; row[3] = A.w; row[4] = e1;
        row[5] = A.x - mx; row[6] = A.y - my; row[7] = A.z - mz;
        row[8] = fcx; row[9] = fcy; row[10] = fcz;
        #pragma unroll
        for (int t = 11; t < 16; t++) row[t] = 0.f;
    }
    __builtin_amdgcn_wave_barrier();

    v8s fh0 = {0,0,0,0,0,0,0,0}, fl0 = {0,0,0,0,0,0,0,0};
    v8s fh1 = {0,0,0,0,0,0,0,0}, fl1 = {0,0,0,0,0,0,0,0};
    if (q < 2) {
        float f8[8];
        #pragma unroll
        for (int i = 0; i < 8; i++) f8[i] = spf[m][q * 8 + i];
        split8(f8, fh0, fl0);
        #pragma unroll
        for (int i = 0; i < 8; i++) f8[i] = spf[16 + m][q * 8 + i];
        split8(f8, fh1, fl1);
    }
    v4f d0[4], d1[4];
    #pragma unroll
    for (int t = 0; t < 4; t++) {
        v8s bh = w1frag[(t * 2 + 0) * 64 + j];
        v8s bl = w1frag[(t * 2 + 1) * 64 + j];
        v4f a0 = {0.f, 0.f, 0.f, 0.f}, a1 = {0.f, 0.f, 0.f, 0.f};
        a0 = __builtin_amdgcn_mfma_f32_16x16x32_bf16(fh0, bh, a0, 0, 0, 0);
        a0 = __builtin_amdgcn_mfma_f32_16x16x32_bf16(fl0, bh, a0, 0, 0, 0);
        a0 = __builtin_amdgcn_mfma_f32_16x16x32_bf16(fh0, bl, a0, 0, 0, 0);
        a1 = __builtin_amdgcn_mfma_f32_16x16x32_bf16(fh1, bh, a1, 0, 0, 0);
        a1 = __builtin_amdgcn_mfma_f32_16x16x32_bf16(fl1, bh, a1, 0, 0, 0);
        a1 = __builtin_amdgcn_mfma_f32_16x16x32_bf16(fh1, bl, a1, 0, 0, 0);
        d0[t] = a0; d1[t] = a1;
    }
    __builtin_amdgcn_wave_barrier();   // feature reads done before overwrite
    #pragma unroll
    for (int t = 0; t < 4; t++)
        #pragma unroll
        for (int r = 0; r < 4; r++) {
            spf[q * 4 + r][t * 16 + m]      = fmaxf(d0[t][r], 0.f);
            spf[16 + q * 4 + r][t * 16 + m] = fmaxf(d1[t][r], 0.f);
        }
    __builtin_amdgcn_wave_barrier();

    // ---- phase 2: A-frags for both tiles; shared w2 frags in the t-loop
    float vf0[16], vf1[16];
    if (ext0) {
        const float* vr = v1c + (size_t)bidx0 * 64 + q * 8;
        #pragma unroll
        for (int c = 0; c < 2; c++)
            #pragma unroll
            for (int i = 0; i < 8; i++) vf0[c * 8 + i] = vr[c * 32 + i];
    }
    if (ext1) {
        const float* vr = v1c + (size_t)bidx1 * 64 + q * 8;
        #pragma unroll
        for (int c = 0; c < 2; c++)
            #pragma unroll
            for (int i = 0; i < 8; i++) vf1[c * 8 + i] = vr[c * 32 + i];
    }

    v8s ah0[4], al0[4], ah1[4], al1[4];
    #pragma unroll
    for (int c = 0; c < 2; c++) {
        float f[8];
        #pragma unroll
        for (int i = 0; i < 8; i++) f[i] = spf[m][c * 32 + q * 8 + i];
        split8(f, ah0[c], al0[c]);
        #pragma unroll
        for (int i = 0; i < 8; i++) f[i] = spf[16 + m][c * 32 + q * 8 + i];
        split8(f, ah1[c], al1[c]);
    }
    if (!ext0) {
        #pragma unroll
        for (int i = 0; i < 16; i++) vf0[i] = 0.f;
        for (int p = s0_; p < e0_; p++) {
            const float* row = spf[p];
            #pragma unroll
            for (int i = 0; i < 8; i++) {
                vf0[i]     = fmaxf(vf0[i],     row[q * 8 + i]);
                vf0[8 + i] = fmaxf(vf0[8 + i], row[32 + q * 8 + i]);
            }
        }
    }
    if (!ext1) {
        #pragma unroll
        for (int i = 0; i < 16; i++) vf1[i] = 0.f;
        for (int p = s1_; p < e1_; p++) {
            const float* row = spf[p];
            #pragma unroll
            for (int i = 0; i < 8; i++) {
                vf1[i]     = fmaxf(vf1[i],     row[q * 8 + i]);
                vf1[8 + i] = fmaxf(vf1[8 + i], row[32 + q * 8 + i]);
            }
        }
    }
    split8(vf0 + 0, ah0[2], al0[2]);
    split8(vf0 + 8, ah0[3], al0[3]);
    split8(vf1 + 0, ah1[2], al1[2]);
    split8(vf1 + 8, ah1[3], al1[3]);
    __builtin_amdgcn_wave_barrier();   // A reads done before D overwrites

    #pragma unroll
    for (int t = 0; t < 4; t++) {
        v8s bh[4], bl[4];
        #pragma unroll
        for (int c = 0; c < 4; c++) {
            bh[c] = w2frag[((t * 4 + c) * 2 + 0) * 64 + j];
            bl[c] = w2frag[((t * 4 + c) * 2 + 1) * 64 + j];
        }
        v4f a0 = {0.f, 0.f, 0.f, 0.f}, a1 = {0.f, 0.f, 0.f, 0.f};
        #pragma unroll
        for (int c = 0; c < 4; c++) {
            a0 = __builtin_amdgcn_mfma_f32_16x16x32_bf16(ah0[c], bh[c], a0, 0, 0, 0);
            a0 = __builtin_amdgcn_mfma_f32_16x16x32_bf16(al0[c], bh[c], a0, 0, 0, 0);
            a0 = __builtin_amdgcn_mfma_f32_16x16x32_bf16(ah0[c], bl[c], a0, 0, 0, 0);
            a1 = __builtin_amdgcn_mfma_f32_16x16x32_bf16(ah1[c], bh[c], a1, 0, 0, 0);
            a1 = __builtin_amdgcn_mfma_f32_16x16x32_bf16(al1[c], bh[c], a1, 0, 0, 0);
            a1 = __builtin_amdgcn_mfma_f32_16x16x32_bf16(ah1[c], bl[c], a1, 0, 0, 0);
        }
        #pragma unroll
        for (int r = 0; r < 4; r++) {
            spf[q * 4 + r][t * 16 + m]      = a0[r];
            spf[16 + q * 4 + r][t * 16 + m] = a1[r];
        }
    }
    __builtin_amdgcn_wave_barrier();

    // ---- epilogue: per-run serial segment-max store (run0 then run1)
    {
        int vprev = first0;
        float smax = -3.4e38f;
        for (int p = 0; p < 16; p++) {
            int vp = rli(vx, p);
            if (vp != vprev) {
                float r = fmaxf(smax, 0.f);
                size_t o = (size_t)vprev * 64 + j;
                bool ua = (vprev == first0 && firstExt0) ||
                          (vprev == last0 && lastExt0);
                if (ua) atomicMax((int*)out + o, __float_as_int(r));
                else out[o] = r;
                vprev = vp; smax = -3.4e38f;
            }
            smax = fmaxf(smax, spf[p][j]);
        }
        float r = fmaxf(smax, 0.f);
        size_t o = (size_t)vprev * 64 + j;
        bool ua = (vprev == first0 && firstExt0) ||
                  (vprev == last0 && lastExt0);
        if (ua) atomicMax((int*)out + o, __float_as_int(r));
        else out[o] = r;
    }
    {
        int vprev = first1;
        float smax = -3.4e38f;
        for (int p = 16; p < 32; p++) {
            int vp = rli(vx, p);
            if (vp != vprev) {
                float r = fmaxf(smax, 0.f);
                size_t o = (size_t)vprev * 64 + j;
                bool ua = (vprev == first1 && firstExt1) ||
                          (vprev == last1 && lastExt1);
                if (ua) atomicMax((int*)out + o, __float_as_int(r));
                else out[o] = r;
                vprev = vp; smax = -3.4e38f;
            }
            smax = fmaxf(smax, spf[p][j]);
        }
        float r = fmaxf(smax, 0.f);
        size_t o = (size_t)vprev * 64 + j;
        bool ua = (vprev == first1 && firstExt1) ||
                  (vprev == last1 && lastExt1);
        if (ua) atomicMax((int*)out + o, __float_as_int(r));
        else out[o] = r;
    }
}

extern "C" void kernel_launch(void* const* d_in, const int* in_sizes, int n_in,
                              void* d_out, int out_size, void* d_ws, size_t ws_size,
                              hipStream_t stream) {
    const float* pts = (const float*)d_in[0];
    const float* W1  = (const float*)d_in[1];
    const float* W2  = (const float*)d_in[2];
    float* out = (float*)d_out;

    float4* vmc    = (float4*)d_ws;                         // NRUNS float4 (400 KB)
    float*  v1c    = (float*)(vmc + NRUNS);                 // NRUNS*64 (6.4 MB)
    float4* pos4   = (float4*)(v1c + (size_t)NRUNS * 64);   // NPTS float4
    float*  e1b    = (float*)(pos4 + NPTS);                 // NPTS
    int*    cellb  = (int*)(e1b + NPTS);                    // NPTS
    int*    rankb  = cellb + NPTS;                          // NPTS
    int*    cellu  = rankb + NPTS;                          // NPTS
    v8s*    w2frag = (v8s*)(cellu + NPTS);                  // 2048 v8s
    v8s*    w1frag = w2frag + 2048;                         // 512 v8s
    int*    cnt    = (int*)(w1frag + 512);                  // CANVAS
    int*    gcur   = cnt + CANVASc;                         // 1
    int*    cursor = gcur + 1;                              // CANVAS

    hipMemsetAsync(cnt, 0, (size_t)(CANVASc + 1) * 4, stream);   // cnt + gcur

    k_stats  <<<GPTS + 5, 256, 0, stream>>>(pts, cnt, rankb, cellu,
                                            W1, W2, w1frag, w2frag);
    k_alloc  <<<GVOX, 256, 0, stream>>>(cnt, cursor, gcur, (float4*)out);
    k_scatter<<<GPTS, 256, 0, stream>>>(pts, cursor, rankb, cellu,
                                        pos4, e1b, cellb);
    kS       <<<GBND, 256, 0, stream>>>(cnt, cursor, pos4, e1b, cellb,
                                        W1, vmc, v1c, out);
    kB       <<<GKB, 128, 0, stream>>>(pos4, e1b, cellb, vmc, w1frag,
                                       w2frag, v1c, out);
}